// Round 5
// baseline (1120.995 us; speedup 1.0000x reference)
//
#include <hip/hip_runtime.h>
#include <math.h>

#define TSAMP 30
#define NGRP  5          // t-groups
#define TPG   6          // t's per group (NGRP*TPG == TSAMP)
#define FEPS  1e-15f

typedef float vfloat4 __attribute__((ext_vector_type(4)));  // clang-native, nontemporal-ok

// softplus(x) = log1p(exp(x)), stable, 1 exp + 1 log
__device__ __forceinline__ float softplus(float x) {
    return fmaxf(x, 0.0f) + __logf(1.0f + __expf(-fabsf(x)));
}

// Fused kernel: grid = NGRP * pblk blocks. g = bid % NGRP owns t in [g*TPG, ...).
//   acc[k]  = sum_i -softplus(d_i + ss_i*(n0-n1))   (t = g*TPG+k)
//   g==0:    u = sum_i -softplus(d_i),  vd = sum_i (exp(var_i)-1)
// Per-block partials land in partial[32][pblk]; the last block to finish
// (ticket counter) reduces all partials in fixed order and writes out[0].
__global__ __launch_bounds__(256) void bcc_fused(
    const float4* __restrict__ logit4,   // [npair]
    const float2* __restrict__ var2,     // [npair]
    const int2*   __restrict__ true2,    // [npair]
    const vfloat4* __restrict__ noise4,  // [TSAMP][npair]
    float* __restrict__ partial,         // [32][pblk]
    unsigned int* __restrict__ counter,  // [1], zeroed before launch
    float* __restrict__ out,
    int npair, int pblk, float invN)
{
    const int g     = blockIdx.x % NGRP;
    const int pb    = blockIdx.x / NGRP;
    const int tbase = g * TPG;

    float acc[TPG];
    #pragma unroll
    for (int k = 0; k < TPG; ++k) acc[k] = 0.0f;
    float u_acc = 0.0f, vd_acc = 0.0f;

    const int pstride = pblk * 256;
    const vfloat4* nbase = noise4 + (size_t)tbase * (size_t)npair;

    int p = pb * 256 + (int)threadIdx.x;

    // dual-pair main body: issue all 18 loads before consuming (MLP)
    for (; p + pstride < npair; p += 2 * pstride) {
        const int pA = p, pB = p + pstride;
        const float4 lgA = logit4[pA];
        const float2 vA  = var2[pA];
        const int2   yA  = true2[pA];
        const float4 lgB = logit4[pB];
        const float2 vB  = var2[pB];
        const int2   yB  = true2[pB];
        vfloat4 nzA[TPG], nzB[TPG];
        #pragma unroll
        for (int k = 0; k < TPG; ++k)
            nzA[k] = __builtin_nontemporal_load(&nbase[(size_t)k * (size_t)npair + pA]);
        #pragma unroll
        for (int k = 0; k < TPG; ++k)
            nzB[k] = __builtin_nontemporal_load(&nbase[(size_t)k * (size_t)npair + pB]);

        const float sgA0 = yA.x ? 1.0f : -1.0f;
        const float dA0  = sgA0 * (lgA.x - lgA.y);
        const float ssA0 = sgA0 * (__fsqrt_rn(vA.x) + FEPS);
        const float sgA1 = yA.y ? 1.0f : -1.0f;
        const float dA1  = sgA1 * (lgA.z - lgA.w);
        const float ssA1 = sgA1 * (__fsqrt_rn(vA.y) + FEPS);
        const float sgB0 = yB.x ? 1.0f : -1.0f;
        const float dB0  = sgB0 * (lgB.x - lgB.y);
        const float ssB0 = sgB0 * (__fsqrt_rn(vB.x) + FEPS);
        const float sgB1 = yB.y ? 1.0f : -1.0f;
        const float dB1  = sgB1 * (lgB.z - lgB.w);
        const float ssB1 = sgB1 * (__fsqrt_rn(vB.y) + FEPS);

        if (g == 0) {
            vd_acc += (__expf(vA.x) - 1.0f) + (__expf(vA.y) - 1.0f)
                    + (__expf(vB.x) - 1.0f) + (__expf(vB.y) - 1.0f);
            u_acc  -= softplus(dA0) + softplus(dA1) + softplus(dB0) + softplus(dB1);
        }
        #pragma unroll
        for (int k = 0; k < TPG; ++k) {
            acc[k] -= softplus(fmaf(ssA0, nzA[k].x - nzA[k].y, dA0))
                    + softplus(fmaf(ssA1, nzA[k].z - nzA[k].w, dA1))
                    + softplus(fmaf(ssB0, nzB[k].x - nzB[k].y, dB0))
                    + softplus(fmaf(ssB1, nzB[k].z - nzB[k].w, dB1));
        }
    }
    // single-pair tail
    if (p < npair) {
        const float4 lg = logit4[p];
        const float2 v  = var2[p];
        const int2   yy = true2[p];
        vfloat4 nz[TPG];
        #pragma unroll
        for (int k = 0; k < TPG; ++k)
            nz[k] = __builtin_nontemporal_load(&nbase[(size_t)k * (size_t)npair + p]);
        const float sg0 = yy.x ? 1.0f : -1.0f;
        const float d0  = sg0 * (lg.x - lg.y);
        const float ss0 = sg0 * (__fsqrt_rn(v.x) + FEPS);
        const float sg1 = yy.y ? 1.0f : -1.0f;
        const float d1  = sg1 * (lg.z - lg.w);
        const float ss1 = sg1 * (__fsqrt_rn(v.y) + FEPS);
        if (g == 0) {
            vd_acc += (__expf(v.x) - 1.0f) + (__expf(v.y) - 1.0f);
            u_acc  -= softplus(d0) + softplus(d1);
        }
        #pragma unroll
        for (int k = 0; k < TPG; ++k) {
            acc[k] -= softplus(fmaf(ss0, nz[k].x - nz[k].y, d0))
                    + softplus(fmaf(ss1, nz[k].z - nz[k].w, d1));
        }
    }

    // ---- block reduce TPG+2 slots (deterministic) ----
    __shared__ float s_part[4][TPG + 2];
    const int lane = threadIdx.x & 63;
    const int wav  = threadIdx.x >> 6;
    #pragma unroll
    for (int a = 0; a < TPG + 2; ++a) {
        float vv = (a < TPG) ? acc[a] : ((a == TPG) ? u_acc : vd_acc);
        #pragma unroll
        for (int off = 32; off >= 1; off >>= 1)
            vv += __shfl_down(vv, off, 64);
        if (lane == 0) s_part[wav][a] = vv;
    }
    __syncthreads();
    if (threadIdx.x < TPG + 2) {
        const int a = threadIdx.x;
        const float s = s_part[0][a] + s_part[1][a] + s_part[2][a] + s_part[3][a];
        if (a < TPG)
            partial[(size_t)(tbase + a) * (size_t)pblk + pb] = s;
        else if (g == 0)
            partial[(size_t)(TSAMP + (a - TPG)) * (size_t)pblk + pb] = s;
    }

    // ---- last-block-done: final reduce + epilogue ----
    __threadfence();   // release our partial writes device-wide
    __shared__ unsigned s_ticket;
    if (threadIdx.x == 0)
        s_ticket = __hip_atomic_fetch_add(counter, 1u, __ATOMIC_ACQ_REL,
                                          __HIP_MEMORY_SCOPE_AGENT);
    __syncthreads();
    if (s_ticket == (unsigned)(gridDim.x - 1)) {
        __threadfence();   // acquire: see all blocks' partial writes

        const int a = threadIdx.x >> 3;   // slot 0..31
        const int k = threadIdx.x & 7;    // 8 threads per slot
        float s = 0.0f;
        for (int j = k; j < pblk; j += 8)
            s += partial[(size_t)a * (size_t)pblk + j];
        s += __shfl_down(s, 4, 64);
        s += __shfl_down(s, 2, 64);
        s += __shfl_down(s, 1, 64);
        __shared__ float res[32];
        if (k == 0) res[a] = s;
        __syncthreads();
        if (threadIdx.x == 0) {
            const float U  = -res[30] * invN;          // undistorted_loss
            const float vd =  res[31] * invN;          // mean variance_depressor
            float mc_sum = 0.0f;
            #pragma unroll
            for (int t = 0; t < TSAMP; ++t) {
                const float D = -res[t] * invN;        // distorted_loss[t]
                const float x = U - D;
                const float e = (x > 0.0f) ? x : expm1f(x);   // elu(x)
                mc_sum += -e;                           // monte_carlo[t]
            }
            const float variance_loss = (mc_sum / (float)TSAMP) * U;
            out[0] = variance_loss + U + vd;
        }
    }
}

extern "C" void kernel_launch(void* const* d_in, const int* in_sizes, int n_in,
                              void* d_out, int out_size, void* d_ws, size_t ws_size,
                              hipStream_t stream) {
    const float* logit = (const float*)d_in[0];   // [N,2] f32
    const float* var   = (const float*)d_in[1];   // [N,1] f32
    const int*   tru   = (const int*)d_in[2];     // [N]   i32
    const float* noise = (const float*)d_in[3];   // [30,N,2] f32
    float* out = (float*)d_out;

    const int N = in_sizes[1];          // var has N elements
    const int npair = N / 2;

    int pblk = 1024;                    // dual body covers 2 pairs/thread
    {
        int maxp = (npair + 255) / 256;
        if (pblk > maxp) pblk = maxp;
        const size_t need = (size_t)32 * (size_t)pblk * sizeof(float) + 64;
        if (ws_size < need) {
            pblk = (int)((ws_size - 64) / (32 * sizeof(float)));
            if (pblk < 1) pblk = 1;
        }
    }
    float* partial = (float*)d_ws;                              // [32][pblk]
    unsigned int* counter = (unsigned int*)(partial + (size_t)32 * (size_t)pblk);

    (void)hipMemsetAsync(counter, 0, sizeof(unsigned int), stream);

    bcc_fused<<<NGRP * pblk, 256, 0, stream>>>(
        (const float4*)logit, (const float2*)var, (const int2*)tru,
        (const vfloat4*)noise, partial, counter, out,
        npair, pblk, 1.0f / (float)N);
}

// Round 6
// 877.334 us; speedup vs baseline: 1.2777x; 1.2777x over previous
//
#include <hip/hip_runtime.h>
#include <math.h>

#define TSAMP 30
#define NGRP  5          // t-groups
#define TPG   6          // t's per group (NGRP*TPG == TSAMP)
#define FEPS  1e-15f

// softplus(x) = log1p(exp(x)), stable, 1 exp + 1 log
__device__ __forceinline__ float softplus(float x) {
    return fmaxf(x, 0.0f) + __logf(1.0f + __expf(-fabsf(x)));
}

// Fused kernel: grid = NGRP * pblk blocks. g = bid % NGRP owns t in [g*TPG, ...).
//   acc[k]  = sum_i -softplus(d_i + ss_i*(n0-n1))   (t = g*TPG+k)
//   g==0:    u = sum_i -softplus(d_i),  vd = sum_i (exp(var_i)-1)
// Per-block partials land in partial[32][pblk]; the last block to finish
// (ticket counter) reduces all partials in fixed order and writes out[0].
// NOTE: plain cached loads only — __builtin_nontemporal_load on gfx950
// turned streaming reads into latency-serialized uncached accesses (161 GB/s).
__global__ __launch_bounds__(256) void bcc_fused(
    const float4* __restrict__ logit4,   // [npair]
    const float2* __restrict__ var2,     // [npair]
    const int2*   __restrict__ true2,    // [npair]
    const float4* __restrict__ noise4,   // [TSAMP][npair]
    float* __restrict__ partial,         // [32][pblk]
    unsigned int* __restrict__ counter,  // [1], zeroed before launch
    float* __restrict__ out,
    int npair, int pblk, float invN)
{
    const int g     = blockIdx.x % NGRP;
    const int pb    = blockIdx.x / NGRP;
    const int tbase = g * TPG;

    float acc[TPG];
    #pragma unroll
    for (int k = 0; k < TPG; ++k) acc[k] = 0.0f;
    float u_acc = 0.0f, vd_acc = 0.0f;

    const int pstride = pblk * 256;
    const float4* nbase = noise4 + (size_t)tbase * (size_t)npair;

    int p = pb * 256 + (int)threadIdx.x;

    // dual-pair main body: issue all 18 loads before consuming (MLP)
    for (; p + pstride < npair; p += 2 * pstride) {
        const int pA = p, pB = p + pstride;
        const float4 lgA = logit4[pA];
        const float2 vA  = var2[pA];
        const int2   yA  = true2[pA];
        const float4 lgB = logit4[pB];
        const float2 vB  = var2[pB];
        const int2   yB  = true2[pB];
        float4 nzA[TPG], nzB[TPG];
        #pragma unroll
        for (int k = 0; k < TPG; ++k)
            nzA[k] = nbase[(size_t)k * (size_t)npair + pA];
        #pragma unroll
        for (int k = 0; k < TPG; ++k)
            nzB[k] = nbase[(size_t)k * (size_t)npair + pB];

        const float sgA0 = yA.x ? 1.0f : -1.0f;
        const float dA0  = sgA0 * (lgA.x - lgA.y);
        const float ssA0 = sgA0 * (__fsqrt_rn(vA.x) + FEPS);
        const float sgA1 = yA.y ? 1.0f : -1.0f;
        const float dA1  = sgA1 * (lgA.z - lgA.w);
        const float ssA1 = sgA1 * (__fsqrt_rn(vA.y) + FEPS);
        const float sgB0 = yB.x ? 1.0f : -1.0f;
        const float dB0  = sgB0 * (lgB.x - lgB.y);
        const float ssB0 = sgB0 * (__fsqrt_rn(vB.x) + FEPS);
        const float sgB1 = yB.y ? 1.0f : -1.0f;
        const float dB1  = sgB1 * (lgB.z - lgB.w);
        const float ssB1 = sgB1 * (__fsqrt_rn(vB.y) + FEPS);

        if (g == 0) {
            vd_acc += (__expf(vA.x) - 1.0f) + (__expf(vA.y) - 1.0f)
                    + (__expf(vB.x) - 1.0f) + (__expf(vB.y) - 1.0f);
            u_acc  -= softplus(dA0) + softplus(dA1) + softplus(dB0) + softplus(dB1);
        }
        #pragma unroll
        for (int k = 0; k < TPG; ++k) {
            acc[k] -= softplus(fmaf(ssA0, nzA[k].x - nzA[k].y, dA0))
                    + softplus(fmaf(ssA1, nzA[k].z - nzA[k].w, dA1))
                    + softplus(fmaf(ssB0, nzB[k].x - nzB[k].y, dB0))
                    + softplus(fmaf(ssB1, nzB[k].z - nzB[k].w, dB1));
        }
    }
    // single-pair tail
    if (p < npair) {
        const float4 lg = logit4[p];
        const float2 v  = var2[p];
        const int2   yy = true2[p];
        float4 nz[TPG];
        #pragma unroll
        for (int k = 0; k < TPG; ++k)
            nz[k] = nbase[(size_t)k * (size_t)npair + p];
        const float sg0 = yy.x ? 1.0f : -1.0f;
        const float d0  = sg0 * (lg.x - lg.y);
        const float ss0 = sg0 * (__fsqrt_rn(v.x) + FEPS);
        const float sg1 = yy.y ? 1.0f : -1.0f;
        const float d1  = sg1 * (lg.z - lg.w);
        const float ss1 = sg1 * (__fsqrt_rn(v.y) + FEPS);
        if (g == 0) {
            vd_acc += (__expf(v.x) - 1.0f) + (__expf(v.y) - 1.0f);
            u_acc  -= softplus(d0) + softplus(d1);
        }
        #pragma unroll
        for (int k = 0; k < TPG; ++k) {
            acc[k] -= softplus(fmaf(ss0, nz[k].x - nz[k].y, d0))
                    + softplus(fmaf(ss1, nz[k].z - nz[k].w, d1));
        }
    }

    // ---- block reduce TPG+2 slots (deterministic) ----
    __shared__ float s_part[4][TPG + 2];
    const int lane = threadIdx.x & 63;
    const int wav  = threadIdx.x >> 6;
    #pragma unroll
    for (int a = 0; a < TPG + 2; ++a) {
        float vv = (a < TPG) ? acc[a] : ((a == TPG) ? u_acc : vd_acc);
        #pragma unroll
        for (int off = 32; off >= 1; off >>= 1)
            vv += __shfl_down(vv, off, 64);
        if (lane == 0) s_part[wav][a] = vv;
    }
    __syncthreads();
    if (threadIdx.x < TPG + 2) {
        const int a = threadIdx.x;
        const float s = s_part[0][a] + s_part[1][a] + s_part[2][a] + s_part[3][a];
        if (a < TPG)
            partial[(size_t)(tbase + a) * (size_t)pblk + pb] = s;
        else if (g == 0)
            partial[(size_t)(TSAMP + (a - TPG)) * (size_t)pblk + pb] = s;
    }

    // ---- last-block-done: final reduce + epilogue ----
    __threadfence();   // release our partial writes device-wide
    __shared__ unsigned s_ticket;
    if (threadIdx.x == 0)
        s_ticket = __hip_atomic_fetch_add(counter, 1u, __ATOMIC_ACQ_REL,
                                          __HIP_MEMORY_SCOPE_AGENT);
    __syncthreads();
    if (s_ticket == (unsigned)(gridDim.x - 1)) {
        __threadfence();   // acquire: see all blocks' partial writes

        const int a = threadIdx.x >> 3;   // slot 0..31
        const int k = threadIdx.x & 7;    // 8 threads per slot
        float s = 0.0f;
        for (int j = k; j < pblk; j += 8)
            s += partial[(size_t)a * (size_t)pblk + j];
        s += __shfl_down(s, 4, 64);
        s += __shfl_down(s, 2, 64);
        s += __shfl_down(s, 1, 64);
        __shared__ float res[32];
        if (k == 0) res[a] = s;
        __syncthreads();
        if (threadIdx.x == 0) {
            const float U  = -res[30] * invN;          // undistorted_loss
            const float vd =  res[31] * invN;          // mean variance_depressor
            float mc_sum = 0.0f;
            #pragma unroll
            for (int t = 0; t < TSAMP; ++t) {
                const float D = -res[t] * invN;        // distorted_loss[t]
                const float x = U - D;
                const float e = (x > 0.0f) ? x : expm1f(x);   // elu(x)
                mc_sum += -e;                           // monte_carlo[t]
            }
            const float variance_loss = (mc_sum / (float)TSAMP) * U;
            out[0] = variance_loss + U + vd;
        }
    }
}

extern "C" void kernel_launch(void* const* d_in, const int* in_sizes, int n_in,
                              void* d_out, int out_size, void* d_ws, size_t ws_size,
                              hipStream_t stream) {
    const float* logit = (const float*)d_in[0];   // [N,2] f32
    const float* var   = (const float*)d_in[1];   // [N,1] f32
    const int*   tru   = (const int*)d_in[2];     // [N]   i32
    const float* noise = (const float*)d_in[3];   // [30,N,2] f32
    float* out = (float*)d_out;

    const int N = in_sizes[1];          // var has N elements
    const int npair = N / 2;

    int pblk = 1024;                    // dual body covers 2 pairs/thread
    {
        int maxp = (npair + 255) / 256;
        if (pblk > maxp) pblk = maxp;
        const size_t need = (size_t)32 * (size_t)pblk * sizeof(float) + 64;
        if (ws_size < need) {
            pblk = (int)((ws_size - 64) / (32 * sizeof(float)));
            if (pblk < 1) pblk = 1;
        }
    }
    float* partial = (float*)d_ws;                              // [32][pblk]
    unsigned int* counter = (unsigned int*)(partial + (size_t)32 * (size_t)pblk);

    (void)hipMemsetAsync(counter, 0, sizeof(unsigned int), stream);

    bcc_fused<<<NGRP * pblk, 256, 0, stream>>>(
        (const float4*)logit, (const float2*)var, (const int2*)tru,
        (const float4*)noise, partial, counter, out,
        npair, pblk, 1.0f / (float)N);
}

// Round 7
// 65.152 us; speedup vs baseline: 17.2059x; 13.4660x over previous
//
#include <hip/hip_runtime.h>
#include <math.h>

#define TSAMP 30
#define NGRP  5          // t-groups
#define TPG   6          // t's per group (NGRP*TPG == TSAMP)
#define FEPS  1e-15f

// softplus(x) = log1p(exp(x)), stable, 1 exp + 1 log
__device__ __forceinline__ float softplus(float x) {
    return fmaxf(x, 0.0f) + __logf(1.0f + __expf(-fabsf(x)));
}

// Kernel 1: grid = (NGRP * pblk) blocks. g = bid % NGRP owns t in [g*TPG, g*TPG+TPG).
// Adjacent blocks are different groups on the same p-range -> param re-reads hit
// L2/L3; noise is read exactly once chip-wide.
// NOTE (R5/R6 lesson): no dual-pair depth-12 arrays, no fused epilogue with
// __threadfence — that bundle ran at 163 GB/s (latency-serialized).
__global__ __launch_bounds__(256) void bcc_partial(
    const float4* __restrict__ logit4,   // [npair]
    const float2* __restrict__ var2,     // [npair]
    const int2*   __restrict__ true2,    // [npair]
    const float4* __restrict__ noise4,   // [TSAMP][npair]
    float* __restrict__ partial,         // [32][pblk]
    int npair, int pblk)
{
    const int g     = blockIdx.x % NGRP;
    const int pb    = blockIdx.x / NGRP;
    const int tbase = g * TPG;

    float acc[TPG];
    #pragma unroll
    for (int k = 0; k < TPG; ++k) acc[k] = 0.0f;
    float u_acc = 0.0f, vd_acc = 0.0f;

    const int pstride = pblk * 256;
    const float4* nbase = noise4 + (size_t)tbase * (size_t)npair;

    for (int p = pb * 256 + threadIdx.x; p < npair; p += pstride) {
        const float4 lg = logit4[p];
        const float2 v  = var2[p];
        const int2   yy = true2[p];

        // issue all 6 noise loads before the param-dependent math (MLP probe)
        float4 nz[TPG];
        #pragma unroll
        for (int k = 0; k < TPG; ++k)
            nz[k] = nbase[(size_t)k * (size_t)npair + p];

        const float sg0 = yy.x ? 1.0f : -1.0f;
        const float d0  = sg0 * (lg.x - lg.y);
        const float ss0 = sg0 * (__fsqrt_rn(v.x) + FEPS);
        const float sg1 = yy.y ? 1.0f : -1.0f;
        const float d1  = sg1 * (lg.z - lg.w);
        const float ss1 = sg1 * (__fsqrt_rn(v.y) + FEPS);

        if (g == 0) {
            vd_acc += (__expf(v.x) - 1.0f) + (__expf(v.y) - 1.0f);
            u_acc  -= softplus(d0) + softplus(d1);
        }

        #pragma unroll
        for (int k = 0; k < TPG; ++k) {
            const float x0 = fmaf(ss0, nz[k].x - nz[k].y, d0);
            const float x1 = fmaf(ss1, nz[k].z - nz[k].w, d1);
            acc[k] -= softplus(x0) + softplus(x1);
        }
    }

    // block-reduce TPG+2 slots (deterministic)
    __shared__ float s_part[4][TPG + 2];
    const int lane = threadIdx.x & 63;
    const int wav  = threadIdx.x >> 6;
    #pragma unroll
    for (int a = 0; a < TPG + 2; ++a) {
        float vv = (a < TPG) ? acc[a] : ((a == TPG) ? u_acc : vd_acc);
        #pragma unroll
        for (int off = 32; off >= 1; off >>= 1)
            vv += __shfl_down(vv, off, 64);
        if (lane == 0) s_part[wav][a] = vv;
    }
    __syncthreads();
    if (threadIdx.x < TPG + 2) {
        const int a = threadIdx.x;
        const float s = s_part[0][a] + s_part[1][a] + s_part[2][a] + s_part[3][a];
        if (a < TPG)
            partial[(size_t)(tbase + a) * (size_t)pblk + pb] = s;
        else if (g == 0)
            partial[(size_t)(TSAMP + (a - TPG)) * (size_t)pblk + pb] = s;
    }
}

// Kernel 2: 32 blocks, block a reduces partial[a][0..pblk) -> res32[a].
// float4 row reads (rows are 16B-aligned when pblk % 4 == 0).
__global__ __launch_bounds__(256) void bcc_reduce(
    const float* __restrict__ partial,   // [32][pblk]
    int pblk, float* __restrict__ res32) // [32]
{
    const int a = blockIdx.x;
    const float* row = partial + (size_t)a * (size_t)pblk;
    float s = 0.0f;
    const int nv = pblk >> 2;
    const float4* row4 = (const float4*)row;
    for (int j = threadIdx.x; j < nv; j += 256) {
        const float4 v = row4[j];
        s += (v.x + v.y) + (v.z + v.w);
    }
    for (int j = (nv << 2) + threadIdx.x; j < pblk; j += 256)
        s += row[j];
    #pragma unroll
    for (int off = 32; off >= 1; off >>= 1)
        s += __shfl_down(s, off, 64);
    __shared__ float sw[4];
    if ((threadIdx.x & 63) == 0) sw[threadIdx.x >> 6] = s;
    __syncthreads();
    if (threadIdx.x == 0)
        res32[a] = sw[0] + sw[1] + sw[2] + sw[3];
}

// Kernel 3: scalar epilogue on the 32 reduced sums.
__global__ __launch_bounds__(64) void bcc_epilogue(
    const float* __restrict__ res32, float invN, float* __restrict__ out)
{
    if (threadIdx.x == 0) {
        const float U  = -res32[30] * invN;          // undistorted_loss
        const float vd =  res32[31] * invN;          // mean variance_depressor
        float mc_sum = 0.0f;
        #pragma unroll
        for (int t = 0; t < TSAMP; ++t) {
            const float D = -res32[t] * invN;        // distorted_loss[t]
            const float x = U - D;
            const float e = (x > 0.0f) ? x : expm1f(x);   // elu(x)
            mc_sum += -e;                             // monte_carlo[t]
        }
        const float variance_loss = (mc_sum / (float)TSAMP) * U;
        out[0] = variance_loss + U + vd;
    }
}

extern "C" void kernel_launch(void* const* d_in, const int* in_sizes, int n_in,
                              void* d_out, int out_size, void* d_ws, size_t ws_size,
                              hipStream_t stream) {
    const float* logit = (const float*)d_in[0];   // [N,2] f32
    const float* var   = (const float*)d_in[1];   // [N,1] f32
    const int*   tru   = (const int*)d_in[2];     // [N]   i32
    const float* noise = (const float*)d_in[3];   // [30,N,2] f32
    float* out = (float*)d_out;

    const int N = in_sizes[1];          // var has N elements
    const int npair = N / 2;

    int pblk = 1024;                    // 2 grid-stride iterations per thread
    {
        int maxp = (npair + 255) / 256;
        if (pblk > maxp) pblk = maxp;
        const size_t need = (size_t)32 * (size_t)pblk * sizeof(float) + 32 * sizeof(float);
        if (ws_size < need) {
            pblk = (int)((ws_size - 32 * sizeof(float)) / (32 * sizeof(float)));
            if (pblk < 1) pblk = 1;
        }
    }
    float* partial = (float*)d_ws;                        // [32][pblk]
    float* res32   = partial + (size_t)32 * (size_t)pblk; // [32]

    bcc_partial<<<NGRP * pblk, 256, 0, stream>>>(
        (const float4*)logit, (const float2*)var, (const int2*)tru,
        (const float4*)noise, partial, npair, pblk);

    bcc_reduce<<<32, 256, 0, stream>>>(partial, pblk, res32);

    bcc_epilogue<<<1, 64, 0, stream>>>(res32, 1.0f / (float)N, out);
}